// Round 14
// baseline (149.804 us; speedup 1.0000x reference)
//
#include <hip/hip_runtime.h>

typedef __bf16 bf16;
typedef __bf16 bf16x8 __attribute__((ext_vector_type(8)));
typedef __bf16 bf16x4 __attribute__((ext_vector_type(4)));
typedef __bf16 bf16x2 __attribute__((ext_vector_type(2)));
typedef float  f32x4  __attribute__((ext_vector_type(4)));
typedef unsigned int u32;
typedef u32 u32x4 __attribute__((ext_vector_type(4)));

#define NN_  320
#define CZ_  128
#define H_   4
#define CH_  32
#define LOG2E_ 1.4426950408889634f

__device__ __forceinline__ u32 pack_bf16(float a, float b) {
    bf16x2 t; t[0] = (bf16)a; t[1] = (bf16)b;
    return __builtin_bit_cast(u32, t);
}

// ---------------------------------------------------------------------------
// Kernel 1: QKVG projections. grid 800 x 512 threads (8 waves x 16 rows).
// T14 async-stage split: next mat's weight gather issued during current MFMAs.
// Q: [n][h][q][32] bf16, pre-scaled by log2e/sqrt(32) (exp2-domain scores);
// K: [n][h][kv][32]; V: [n][h][32][kv] (transposed); G: [m][128] sigmoid.
// ---------------------------------------------------------------------------
__global__ __launch_bounds__(512) void qkvg_kernel(
    const float* __restrict__ x,
    const float* __restrict__ wq, const float* __restrict__ wk,
    const float* __restrict__ wv, const float* __restrict__ wg,
    const float* __restrict__ bg,
    bf16* __restrict__ Qp, bf16* __restrict__ Kp,
    bf16* __restrict__ Vp, bf16* __restrict__ Gp)
{
    __shared__ bf16 wl[128][136];   // transposed weight wl[j][k], stride 272B
    const int tid  = threadIdx.x;
    const int lane = tid & 63, wid = tid >> 6;
    const int l15  = lane & 15, l4 = lane >> 4;
    const int m0   = blockIdx.x << 7;   // 128 rows per block

    // x row fragments straight to registers (fp32 -> bf16)
    const int arow = m0 + wid * 16 + l15;
    bf16x8 xf[4];
    #pragma unroll
    for (int ks = 0; ks < 4; ++ks) {
        float4 f0 = *reinterpret_cast<const float4*>(x + (size_t)arow * CZ_ + ks * 32 + l4 * 8);
        float4 f1 = *reinterpret_cast<const float4*>(x + (size_t)arow * CZ_ + ks * 32 + l4 * 8 + 4);
        bf16x8 t;
        t[0]=(bf16)f0.x; t[1]=(bf16)f0.y; t[2]=(bf16)f0.z; t[3]=(bf16)f0.w;
        t[4]=(bf16)f1.x; t[5]=(bf16)f1.y; t[6]=(bf16)f1.z; t[7]=(bf16)f1.w;
        xf[ks] = t;
    }

    // row decompositions (blocks can cross n boundaries: 128 does not divide 320)
    int nQ[4], qQ[4];
    #pragma unroll
    for (int r = 0; r < 4; ++r) {
        int m = m0 + wid * 16 + l4 * 4 + r;
        nQ[r] = m / NN_; qQ[r] = m - nQ[r] * NN_;
    }
    const int nV = arow / NN_, qV = arow - nV * NN_;

    const float* Ws[4] = {wq, wk, wv, wg};

    // prime: mat 0 weight gather into registers
    float pw[8][4];
    #pragma unroll
    for (int it = 0; it < 8; ++it) {
        const int u = tid + (it << 9), j = u & 127, k4 = u >> 7;
        #pragma unroll
        for (int r = 0; r < 4; ++r) pw[it][r] = wq[(k4 * 4 + r) * CZ_ + j];
    }

    #pragma unroll
    for (int mat = 0; mat < 4; ++mat) {
        __syncthreads();
        // write staged registers to LDS (bf16, transposed)
        #pragma unroll
        for (int it = 0; it < 8; ++it) {
            const int u = tid + (it << 9), j = u & 127, k4 = u >> 7;
            bf16x4 t;
            t[0] = (bf16)pw[it][0]; t[1] = (bf16)pw[it][1];
            t[2] = (bf16)pw[it][2]; t[3] = (bf16)pw[it][3];
            *reinterpret_cast<bf16x4*>(&wl[j][k4 * 4]) = t;
        }
        __syncthreads();

        // T14: issue next mat's gather now; latency hides under the MFMAs below
        if (mat < 3) {
            const float* wnext = Ws[mat + 1];
            #pragma unroll
            for (int it = 0; it < 8; ++it) {
                const int u = tid + (it << 9), j = u & 127, k4 = u >> 7;
                #pragma unroll
                for (int r = 0; r < 4; ++r) pw[it][r] = wnext[(k4 * 4 + r) * CZ_ + j];
            }
        }

        f32x4 zero = {0.f, 0.f, 0.f, 0.f};
        f32x4 acc[8];
        #pragma unroll
        for (int ct = 0; ct < 8; ++ct) acc[ct] = zero;

        #pragma unroll
        for (int ks = 0; ks < 4; ++ks) {
            #pragma unroll
            for (int ct = 0; ct < 8; ++ct) {
                bf16x8 wf = *reinterpret_cast<const bf16x8*>(&wl[ct * 16 + l15][ks * 32 + l4 * 8]);
                if (mat == 2)  // swapped: D[cout][m] so the V^T store coalesces
                    acc[ct] = __builtin_amdgcn_mfma_f32_16x16x32_bf16(wf, xf[ks], acc[ct], 0, 0, 0);
                else
                    acc[ct] = __builtin_amdgcn_mfma_f32_16x16x32_bf16(xf[ks], wf, acc[ct], 0, 0, 0);
            }
        }

        if (mat == 0) {
            #pragma unroll
            for (int ct = 0; ct < 8; ++ct) {
                const int cout = ct * 16 + l15, hh = cout >> 5, cc = cout & 31;
                #pragma unroll
                for (int r = 0; r < 4; ++r)
                    Qp[(size_t)((nQ[r] * H_ + hh) * NN_ + qQ[r]) * CH_ + cc] =
                        (bf16)(acc[ct][r] * 0.25500003540695464f);  // log2e/sqrt(32)
            }
        } else if (mat == 1) {
            #pragma unroll
            for (int ct = 0; ct < 8; ++ct) {
                const int cout = ct * 16 + l15, hh = cout >> 5, cc = cout & 31;
                #pragma unroll
                for (int r = 0; r < 4; ++r)
                    Kp[(size_t)((nQ[r] * H_ + hh) * NN_ + qQ[r]) * CH_ + cc] = (bf16)acc[ct][r];
            }
        } else if (mat == 2) {
            // D row = cout = ct*16 + l4*4 + r; D col = m-local = l15 (arow)
            #pragma unroll
            for (int ct = 0; ct < 8; ++ct) {
                #pragma unroll
                for (int r = 0; r < 4; ++r) {
                    const int cout = ct * 16 + l4 * 4 + r, hh = cout >> 5, cc = cout & 31;
                    Vp[(size_t)((nV * H_ + hh) * CH_ + cc) * NN_ + qV] = (bf16)acc[ct][r];
                }
            }
        } else {
            #pragma unroll
            for (int ct = 0; ct < 8; ++ct) {
                const int cout = ct * 16 + l15;
                const float bgj = bg[cout];
                #pragma unroll
                for (int r = 0; r < 4; ++r) {
                    float t = acc[ct][r] + bgj;
                    Gp[(size_t)(m0 + wid * 16 + l4 * 4 + r) * CZ_ + cout] =
                        (bf16)(1.0f / (1.0f + __expf(-t)));
                }
            }
        }
    }
}

// ---------------------------------------------------------------------------
// Kernel 2: fused attention + gating. grid 2560 = (n, h, q-half), 640 thr =
// 10 waves = 5 q-tiles (32 q, dual-qg chains) x 2 KV-HALVES (160 kv = 5 bodies
// per wave -- HALF of R12's serial chain). No-max exp makes kv-partials
// additive: o_tot = o_a + o_b, l_tot = l_a + l_b (exact, no rescale). kvh=1
// waves dump partials into LDS (overlaying the dead K region) and kvh=0 waves
// merge + run the gated epilogue. K padded LDS; V sigma-packed (b128 PV
// reads); exp2-domain scores; ones-MFMA row-sum; setprio.
// Overwrites Gp with o*g (bf16).
// ---------------------------------------------------------------------------
__global__ __launch_bounds__(640, 3) void attn_kernel(
    const bf16* __restrict__ Qp, const bf16* __restrict__ Kp,
    const bf16* __restrict__ Vp, bf16* __restrict__ Gp,
    const float* __restrict__ bias)
{
    __shared__ __align__(16) bf16 smem[23296];   // 46592 B: K 25600 | V 20992
    bf16 (*Kl)[40]  = reinterpret_cast<bf16(*)[40]>(smem);           // [320][40]
    bf16 (*Vl)[328] = reinterpret_cast<bf16(*)[328]>(smem + 12800);  // [32][328]
    const int tid  = threadIdx.x;
    const int lane = tid & 63;
    const int wid  = tid >> 6;            // 0..9
    const int l15  = lane & 15, l4 = lane >> 4;
    // XCD chunking: the 2 q-half blocks of one (n,h) are gid-adjacent -> same
    // XCD -> the duplicate K/V staging hits L2.
    const int gid  = blockIdx.x;
    const int lin  = (gid & 7) * 320 + (gid >> 3);
    const int h    = lin / 640;
    const int rem  = lin - h * 640;
    const int n    = rem >> 1;
    const int half = rem & 1;
    const int qt   = wid % 5;             // q-tile within the half
    const int kvh  = wid / 5;             // kv half (0: kv 0..159, 1: 160..319)

    const size_t nh = (size_t)(n * H_ + h);
    const bf16* Kh = Kp + nh * NN_ * CH_;
    const bf16* Vh = Vp + nh * CH_ * NN_;
    const bf16* Qh = Qp + nh * NN_ * CH_;

    // one-shot cooperative staging: 1280 16B chunks each for K and V^T.
    // V chunk (vr, vc): packed base = (vc>>2)*32 + (m&1)*16 + (m>>1)*4, m=vc&3.
    #pragma unroll
    for (int i = 0; i < 2; ++i) {
        int c  = tid + i * 640;
        int kr = c >> 2, kc = (c & 3) * 8;
        *reinterpret_cast<bf16x8*>(&Kl[kr][kc]) =
            *reinterpret_cast<const bf16x8*>(Kh + kr * CH_ + kc);
        int vr = c / 40, vc = c - vr * 40;
        int m = vc & 3, b32 = vc >> 2;
        bf16x8 g = *reinterpret_cast<const bf16x8*>(Vh + vr * NN_ + vc * 8);
        int base = b32 * 32 + (m & 1) * 16 + (m >> 1) * 4;
        bf16x4 lo; lo[0] = g[0]; lo[1] = g[1]; lo[2] = g[2]; lo[3] = g[3];
        bf16x4 hi; hi[0] = g[4]; hi[1] = g[5]; hi[2] = g[6]; hi[3] = g[7];
        *reinterpret_cast<bf16x4*>(&Vl[vr][base]) = lo;
        *reinterpret_cast<bf16x4*>(&Vl[vr][base + 8]) = hi;
    }
    __syncthreads();

    const f32x4 zero = {0.f, 0.f, 0.f, 0.f};
    bf16x8 onesf;
    #pragma unroll
    for (int i = 0; i < 8; ++i) onesf[i] = (bf16)1.0f;

    // per-qg state (dual independent chains)
    const int qb0 = half * 160 + qt * 32;
    const int kvb = kvh * 160;
    bf16x8 qf[2];
    const float* bq[2];
    f32x4 o0[2], o1[2], ol[2];
    float4 bA0[2], bA1[2], bB0[2], bB1[2];

    #pragma unroll
    for (int qg = 0; qg < 2; ++qg) {
        const int qb = qb0 + qg * 16;
        qf[qg] = *reinterpret_cast<const bf16x8*>(&Qh[(qb + l15) * CH_ + l4 * 8]);
        bq[qg] = bias + ((size_t)h * NN_ + qb + l15) * NN_ + kvb + l4 * 4;
        o0[qg] = zero; o1[qg] = zero; ol[qg] = zero;
        bA0[qg] = *reinterpret_cast<const float4*>(bq[qg]);
        bA1[qg] = *reinterpret_cast<const float4*>(bq[qg] + 16);
        bB0[qg] = *reinterpret_cast<const float4*>(bq[qg] + 32);
        bB1[qg] = *reinterpret_cast<const float4*>(bq[qg] + 48);
    }

#define ATTN_TP(TP, B0, B1, PRE)                                                   \
    {                                                                              \
        const int kvm = kvb + (TP) * 32;                                           \
        bf16x8 kf0 = *reinterpret_cast<const bf16x8*>(&Kl[kvm + l15][l4 * 8]);     \
        bf16x8 kf1 = *reinterpret_cast<const bf16x8*>(&Kl[kvm + 16 + l15][l4 * 8]);\
        bf16x8 vf0 = *reinterpret_cast<const bf16x8*>(&Vl[l15][kvm + l4 * 8]);     \
        bf16x8 vf1 = *reinterpret_cast<const bf16x8*>(&Vl[16 + l15][kvm + l4 * 8]);\
        f32x4 s0[2], s1[2];                                                        \
        __builtin_amdgcn_s_setprio(1);                                             \
        s0[0] = __builtin_amdgcn_mfma_f32_16x16x32_bf16(kf0, qf[0], zero, 0, 0, 0);\
        s1[0] = __builtin_amdgcn_mfma_f32_16x16x32_bf16(kf1, qf[0], zero, 0, 0, 0);\
        s0[1] = __builtin_amdgcn_mfma_f32_16x16x32_bf16(kf0, qf[1], zero, 0, 0, 0);\
        s1[1] = __builtin_amdgcn_mfma_f32_16x16x32_bf16(kf1, qf[1], zero, 0, 0, 0);\
        __builtin_amdgcn_s_setprio(0);                                             \
        _Pragma("unroll")                                                          \
        for (int qg = 0; qg < 2; ++qg) {                                           \
            float p0 = __builtin_amdgcn_exp2f(__builtin_fmaf(B0[qg].x, LOG2E_, s0[qg][0])); \
            float p1 = __builtin_amdgcn_exp2f(__builtin_fmaf(B0[qg].y, LOG2E_, s0[qg][1])); \
            float p2 = __builtin_amdgcn_exp2f(__builtin_fmaf(B0[qg].z, LOG2E_, s0[qg][2])); \
            float p3 = __builtin_amdgcn_exp2f(__builtin_fmaf(B0[qg].w, LOG2E_, s0[qg][3])); \
            float p4 = __builtin_amdgcn_exp2f(__builtin_fmaf(B1[qg].x, LOG2E_, s1[qg][0])); \
            float p5 = __builtin_amdgcn_exp2f(__builtin_fmaf(B1[qg].y, LOG2E_, s1[qg][1])); \
            float p6 = __builtin_amdgcn_exp2f(__builtin_fmaf(B1[qg].z, LOG2E_, s1[qg][2])); \
            float p7 = __builtin_amdgcn_exp2f(__builtin_fmaf(B1[qg].w, LOG2E_, s1[qg][3])); \
            u32x4 ww;                                                              \
            ww[0] = pack_bf16(p0, p1); ww[1] = pack_bf16(p2, p3);                  \
            ww[2] = pack_bf16(p4, p5); ww[3] = pack_bf16(p6, p7);                  \
            bf16x8 pf = __builtin_bit_cast(bf16x8, ww);                            \
            if (PRE) { /* refill for TP+2 (stays inside this kv-half) */           \
                B0[qg] = *reinterpret_cast<const float4*>(bq[qg] + ((TP) + 2) * 32);      \
                B1[qg] = *reinterpret_cast<const float4*>(bq[qg] + ((TP) + 2) * 32 + 16); \
            }                                                                      \
            __builtin_amdgcn_s_setprio(1);                                         \
            ol[qg] = __builtin_amdgcn_mfma_f32_16x16x32_bf16(onesf, pf, ol[qg], 0, 0, 0); \
            o0[qg] = __builtin_amdgcn_mfma_f32_16x16x32_bf16(vf0, pf, o0[qg], 0, 0, 0);   \
            o1[qg] = __builtin_amdgcn_mfma_f32_16x16x32_bf16(vf1, pf, o1[qg], 0, 0, 0);   \
            __builtin_amdgcn_s_setprio(0);                                         \
        }                                                                          \
    }

    ATTN_TP(0, bA0, bA1, true);
    ATTN_TP(1, bB0, bB1, true);
    ATTN_TP(2, bA0, bA1, true);
    ATTN_TP(3, bB0, bB1, false);
    ATTN_TP(4, bA0, bA1, false);
#undef ATTN_TP

    // kv-partial merge: kvh=1 dumps partials into LDS (K region is dead now)
    __syncthreads();
    float* red = reinterpret_cast<float*>(smem);
    float* p = red + (size_t)(qt * 64 + lane) * 20;   // 80B stride, 16B aligned
    if (kvh == 1) {
        *reinterpret_cast<f32x4*>(p)      = o0[0];
        *reinterpret_cast<f32x4*>(p + 4)  = o1[0];
        *reinterpret_cast<f32x4*>(p + 8)  = o0[1];
        *reinterpret_cast<f32x4*>(p + 12) = o1[1];
        p[16] = ol[0][0];
        p[17] = ol[1][0];
    }
    __syncthreads();
    if (kvh == 0) {
        o0[0] += *reinterpret_cast<const f32x4*>(p);
        o1[0] += *reinterpret_cast<const f32x4*>(p + 4);
        o0[1] += *reinterpret_cast<const f32x4*>(p + 8);
        o1[1] += *reinterpret_cast<const f32x4*>(p + 12);
        const float l0 = ol[0][0] + p[16];
        const float l1 = ol[1][0] + p[17];
        #pragma unroll
        for (int qg = 0; qg < 2; ++qg) {
            const int qb = qb0 + qg * 16;
            const size_t gbase = ((size_t)n * NN_ + qb + l15) * CZ_ + h * CH_;
            const bf16x4 g0 = *reinterpret_cast<const bf16x4*>(&Gp[gbase + l4 * 4]);
            const bf16x4 g1 = *reinterpret_cast<const bf16x4*>(&Gp[gbase + 16 + l4 * 4]);
            const float linv = 1.0f / (qg ? l1 : l0);
            bf16x4 h0, h1;
            #pragma unroll
            for (int r = 0; r < 4; ++r) {
                h0[r] = (bf16)(o0[qg][r] * linv * (float)g0[r]);
                h1[r] = (bf16)(o1[qg][r] * linv * (float)g1[r]);
            }
            *reinterpret_cast<bf16x4*>(&Gp[gbase + l4 * 4]) = h0;
            *reinterpret_cast<bf16x4*>(&Gp[gbase + 16 + l4 * 4]) = h1;
        }
    }
}

// ---------------------------------------------------------------------------
// Kernel 3: out = og @ wo + bo (fp32). grid 400 x 512 threads; each block
// processes TWO 128-row tiles with one wo staging.
// ---------------------------------------------------------------------------
__global__ __launch_bounds__(512) void oproj_kernel(
    const bf16* __restrict__ og, const float* __restrict__ wo,
    const float* __restrict__ bo, float* __restrict__ out)
{
    __shared__ bf16 wl[128][136];
    const int tid  = threadIdx.x;
    const int lane = tid & 63, wid = tid >> 6;
    const int l15  = lane & 15, l4 = lane >> 4;

    #pragma unroll
    for (int it = 0; it < 8; ++it) {
        int u  = tid + (it << 9);
        int j  = u & 127, k4 = u >> 7;
        bf16x4 t;
        t[0] = (bf16)wo[(k4 * 4 + 0) * CZ_ + j];
        t[1] = (bf16)wo[(k4 * 4 + 1) * CZ_ + j];
        t[2] = (bf16)wo[(k4 * 4 + 2) * CZ_ + j];
        t[3] = (bf16)wo[(k4 * 4 + 3) * CZ_ + j];
        *reinterpret_cast<bf16x4*>(&wl[j][k4 * 4]) = t;
    }
    __syncthreads();

    #pragma unroll 1
    for (int rt = 0; rt < 2; ++rt) {
        const int m0 = (blockIdx.x << 8) + rt * 128;
        const int arow = m0 + wid * 16 + l15;
        bf16x8 af[4];
        #pragma unroll
        for (int ks = 0; ks < 4; ++ks)
            af[ks] = *reinterpret_cast<const bf16x8*>(&og[(size_t)arow * CZ_ + ks * 32 + l4 * 8]);

        f32x4 zero = {0.f, 0.f, 0.f, 0.f};
        f32x4 acc[8];
        #pragma unroll
        for (int ct = 0; ct < 8; ++ct) acc[ct] = zero;
        #pragma unroll
        for (int ks = 0; ks < 4; ++ks)
            #pragma unroll
            for (int ct = 0; ct < 8; ++ct) {
                bf16x8 wf = *reinterpret_cast<const bf16x8*>(&wl[ct * 16 + l15][ks * 32 + l4 * 8]);
                acc[ct] = __builtin_amdgcn_mfma_f32_16x16x32_bf16(af[ks], wf, acc[ct], 0, 0, 0);
            }

        #pragma unroll
        for (int ct = 0; ct < 8; ++ct) {
            const int cout = ct * 16 + l15;
            const float bov = bo[cout];
            #pragma unroll
            for (int r = 0; r < 4; ++r)
                out[(size_t)(m0 + wid * 16 + l4 * 4 + r) * CZ_ + cout] = acc[ct][r] + bov;
        }
    }
}

// ---------------------------------------------------------------------------
extern "C" void kernel_launch(void* const* d_in, const int* in_sizes, int n_in,
                              void* d_out, int out_size, void* d_ws, size_t ws_size,
                              hipStream_t stream) {
    (void)in_sizes; (void)n_in; (void)out_size; (void)ws_size;
    const float* x    = (const float*)d_in[0];
    const float* bias = (const float*)d_in[1];
    const float* wq   = (const float*)d_in[2];
    const float* wk   = (const float*)d_in[3];
    const float* wv   = (const float*)d_in[4];
    const float* wg   = (const float*)d_in[5];
    const float* bg   = (const float*)d_in[6];
    const float* wo   = (const float*)d_in[7];
    const float* bo   = (const float*)d_in[8];
    float* out = (float*)d_out;

    const size_t ELEMS = (size_t)NN_ * NN_ * CZ_;
    bf16* Qp = (bf16*)d_ws;          // 26.2 MB
    bf16* Gp = Qp + ELEMS;           // 26.2 MB
    bf16* Kp = (bf16*)d_out;         // scratch until oproj overwrites
    bf16* Vp = Kp + ELEMS;

    qkvg_kernel<<<dim3(800), 512, 0, stream>>>(x, wq, wk, wv, wg, bg, Qp, Kp, Vp, Gp);
    attn_kernel<<<dim3(2560), 640, 0, stream>>>(Qp, Kp, Vp, Gp, bias);
    oproj_kernel<<<dim3(400), 512, 0, stream>>>(Gp, wo, bo, out);
}

// Round 15
// 149.153 us; speedup vs baseline: 1.0044x; 1.0044x over previous
//
#include <hip/hip_runtime.h>

typedef __bf16 bf16;
typedef __bf16 bf16x8 __attribute__((ext_vector_type(8)));
typedef __bf16 bf16x4 __attribute__((ext_vector_type(4)));
typedef __bf16 bf16x2 __attribute__((ext_vector_type(2)));
typedef float  f32x4  __attribute__((ext_vector_type(4)));
typedef unsigned int u32;
typedef u32 u32x4 __attribute__((ext_vector_type(4)));

#define NN_  320
#define CZ_  128
#define H_   4
#define CH_  32
#define LOG2E_ 1.4426950408889634f

__device__ __forceinline__ u32 pack_bf16(float a, float b) {
    bf16x2 t; t[0] = (bf16)a; t[1] = (bf16)b;
    return __builtin_bit_cast(u32, t);
}

// ---------------------------------------------------------------------------
// Kernel 1: QKVG projections. grid 800 x 512 threads (8 waves x 16 rows).
// T14 weight prefetch (next mat's gather issued under current MFMAs) AND
// COALESCED STORES: each mat's output tile round-trips through LDS sb[][] so
// global writes are b128/lane in 16-lane-contiguous chunks (the old path wrote
// per-lane 2B scalars in 32B segments -> ~2x HBM write amplification).
// Q: [n][h][q][32] bf16, pre-scaled by log2e/sqrt(32) (exp2-domain scores);
// K: [n][h][kv][32]; V: [n][h][32][kv] (transposed); G: [m][128] sigmoid.
// ---------------------------------------------------------------------------
__global__ __launch_bounds__(512) void qkvg_kernel(
    const float* __restrict__ x,
    const float* __restrict__ wq, const float* __restrict__ wk,
    const float* __restrict__ wv, const float* __restrict__ wg,
    const float* __restrict__ bg,
    bf16* __restrict__ Qp, bf16* __restrict__ Kp,
    bf16* __restrict__ Vp, bf16* __restrict__ Gp)
{
    __shared__ bf16 wl[128][136];   // transposed weight wl[j][k], stride 272B
    __shared__ bf16 sb[128][132];   // store-transpose buffer, +4 pad
    const int tid  = threadIdx.x;
    const int lane = tid & 63, wid = tid >> 6;
    const int l15  = lane & 15, l4 = lane >> 4;
    const int m0   = blockIdx.x << 7;   // 128 rows per block

    // x row fragments straight to registers (fp32 -> bf16)
    const int arow = m0 + wid * 16 + l15;
    bf16x8 xf[4];
    #pragma unroll
    for (int ks = 0; ks < 4; ++ks) {
        float4 f0 = *reinterpret_cast<const float4*>(x + (size_t)arow * CZ_ + ks * 32 + l4 * 8);
        float4 f1 = *reinterpret_cast<const float4*>(x + (size_t)arow * CZ_ + ks * 32 + l4 * 8 + 4);
        bf16x8 t;
        t[0]=(bf16)f0.x; t[1]=(bf16)f0.y; t[2]=(bf16)f0.z; t[3]=(bf16)f0.w;
        t[4]=(bf16)f1.x; t[5]=(bf16)f1.y; t[6]=(bf16)f1.z; t[7]=(bf16)f1.w;
        xf[ks] = t;
    }

    const float* Ws[4] = {wq, wk, wv, wg};

    // prime: mat 0 weight gather into registers
    float pw[8][4];
    #pragma unroll
    for (int it = 0; it < 8; ++it) {
        const int u = tid + (it << 9), j = u & 127, k4 = u >> 7;
        #pragma unroll
        for (int r = 0; r < 4; ++r) pw[it][r] = wq[(k4 * 4 + r) * CZ_ + j];
    }

    #pragma unroll
    for (int mat = 0; mat < 4; ++mat) {
        __syncthreads();   // protects wl (and sb from previous mat's readers)
        // write staged registers to LDS (bf16, transposed)
        #pragma unroll
        for (int it = 0; it < 8; ++it) {
            const int u = tid + (it << 9), j = u & 127, k4 = u >> 7;
            bf16x4 t;
            t[0] = (bf16)pw[it][0]; t[1] = (bf16)pw[it][1];
            t[2] = (bf16)pw[it][2]; t[3] = (bf16)pw[it][3];
            *reinterpret_cast<bf16x4*>(&wl[j][k4 * 4]) = t;
        }
        __syncthreads();

        // T14: issue next mat's gather now; latency hides under the MFMAs below
        if (mat < 3) {
            const float* wnext = Ws[mat + 1];
            #pragma unroll
            for (int it = 0; it < 8; ++it) {
                const int u = tid + (it << 9), j = u & 127, k4 = u >> 7;
                #pragma unroll
                for (int r = 0; r < 4; ++r) pw[it][r] = wnext[(k4 * 4 + r) * CZ_ + j];
            }
        }

        f32x4 zero = {0.f, 0.f, 0.f, 0.f};
        f32x4 acc[8];
        #pragma unroll
        for (int ct = 0; ct < 8; ++ct) acc[ct] = zero;

        #pragma unroll
        for (int ks = 0; ks < 4; ++ks) {
            #pragma unroll
            for (int ct = 0; ct < 8; ++ct) {
                bf16x8 wf = *reinterpret_cast<const bf16x8*>(&wl[ct * 16 + l15][ks * 32 + l4 * 8]);
                if (mat == 2)  // swapped: D[cout][m] -> V^T tile
                    acc[ct] = __builtin_amdgcn_mfma_f32_16x16x32_bf16(wf, xf[ks], acc[ct], 0, 0, 0);
                else
                    acc[ct] = __builtin_amdgcn_mfma_f32_16x16x32_bf16(xf[ks], wf, acc[ct], 0, 0, 0);
            }
        }

        // acc -> sb (bf16), layout depends on mat
        if (mat == 0) {
            #pragma unroll
            for (int ct = 0; ct < 8; ++ct)
                #pragma unroll
                for (int r = 0; r < 4; ++r)
                    sb[wid * 16 + l4 * 4 + r][ct * 16 + l15] =
                        (bf16)(acc[ct][r] * 0.25500003540695464f);  // log2e/sqrt(32)
        } else if (mat == 1) {
            #pragma unroll
            for (int ct = 0; ct < 8; ++ct)
                #pragma unroll
                for (int r = 0; r < 4; ++r)
                    sb[wid * 16 + l4 * 4 + r][ct * 16 + l15] = (bf16)acc[ct][r];
        } else if (mat == 2) {
            // D[cout][mlocal]: row = ct*16+l4*4+r, col = wid*16+l15
            #pragma unroll
            for (int ct = 0; ct < 8; ++ct)
                #pragma unroll
                for (int r = 0; r < 4; ++r)
                    sb[ct * 16 + l4 * 4 + r][wid * 16 + l15] = (bf16)acc[ct][r];
        } else {
            #pragma unroll
            for (int ct = 0; ct < 8; ++ct) {
                const float bgj = bg[ct * 16 + l15];
                #pragma unroll
                for (int r = 0; r < 4; ++r) {
                    float t = acc[ct][r] + bgj;
                    sb[wid * 16 + l4 * 4 + r][ct * 16 + l15] =
                        (bf16)(1.0f / (1.0f + __expf(-t)));
                }
            }
        }
        __syncthreads();

        // coalesced b128 stores: 2048 8-elem chunks, 4 per thread
        #pragma unroll
        for (int i = 0; i < 4; ++i) {
            const int c   = tid + (i << 9);
            const int row = c >> 4, ck = c & 15;
            bf16x8 v = *reinterpret_cast<const bf16x8*>(&sb[row][ck * 8]);
            if (mat == 0 || mat == 1) {
                const int m = m0 + row, nn2 = m / NN_, qq2 = m - nn2 * NN_;
                bf16* dst = (mat == 0) ? Qp : Kp;
                *reinterpret_cast<bf16x8*>(
                    &dst[((size_t)(nn2 * H_ + (ck >> 2)) * NN_ + qq2) * CH_ + (ck & 3) * 8]) = v;
            } else if (mat == 2) {
                const int mg = m0 + ck * 8;          // 8-chunks never cross n (320%8==0)
                const int nn2 = mg / NN_, qq2 = mg - nn2 * NN_;
                *reinterpret_cast<bf16x8*>(
                    &Vp[((size_t)(nn2 * H_ + (row >> 5)) * CH_ + (row & 31)) * NN_ + qq2]) = v;
            } else {
                *reinterpret_cast<bf16x8*>(&Gp[(size_t)(m0 + row) * CZ_ + ck * 8]) = v;
            }
        }
    }
}

// ---------------------------------------------------------------------------
// Kernel 2: fused attention + gating. EXACTLY R12 (best attn, 80.8us) MINUS
// s_setprio -- isolated A/B: setprio was added in R9 bundled with other
// changes and never tested alone; m190 measured it HURTING barrier-synced
// structures. grid 1280 = (n,h) h-major XCD-pinned, 640 thr = 10 waves.
// K padded LDS; V sigma-packed (b128 PV reads); dual q-group chains;
// exp2-domain scores; ones-MFMA row-sum. Overwrites Gp with o*g (bf16).
// ---------------------------------------------------------------------------
__global__ __launch_bounds__(640, 3) void attn_kernel(
    const bf16* __restrict__ Qp, const bf16* __restrict__ Kp,
    const bf16* __restrict__ Vp, bf16* __restrict__ Gp,
    const float* __restrict__ bias)
{
    __shared__ bf16 Kl[320][40];    // 80B rows
    __shared__ bf16 Vl[32][328];    // 656B rows, sigma-packed cols
    const int tid  = threadIdx.x;
    const int lane = tid & 63;
    const int wid  = tid >> 6;            // 0..9
    const int l15  = lane & 15, l4 = lane >> 4;
    const int gid = blockIdx.x;
    const int lin = (gid & 7) * 160 + (gid >> 3);
    const int h   = lin / NN_;
    const int n   = lin - h * NN_;

    const size_t nh = (size_t)(n * H_ + h);
    const bf16* Kh = Kp + nh * NN_ * CH_;
    const bf16* Vh = Vp + nh * CH_ * NN_;
    const bf16* Qh = Qp + nh * NN_ * CH_;

    // one-shot cooperative staging: 1280 16B chunks each for K and V^T.
    // V chunk (vr, vc): packed base = (vc>>2)*32 + (m&1)*16 + (m>>1)*4, m=vc&3.
    #pragma unroll
    for (int i = 0; i < 2; ++i) {
        int c  = tid + i * 640;
        int kr = c >> 2, kc = (c & 3) * 8;
        *reinterpret_cast<bf16x8*>(&Kl[kr][kc]) =
            *reinterpret_cast<const bf16x8*>(Kh + kr * CH_ + kc);
        int vr = c / 40, vc = c - vr * 40;
        int m = vc & 3, b32 = vc >> 2;
        bf16x8 g = *reinterpret_cast<const bf16x8*>(Vh + vr * NN_ + vc * 8);
        int base = b32 * 32 + (m & 1) * 16 + (m >> 1) * 4;
        bf16x4 lo; lo[0] = g[0]; lo[1] = g[1]; lo[2] = g[2]; lo[3] = g[3];
        bf16x4 hi; hi[0] = g[4]; hi[1] = g[5]; hi[2] = g[6]; hi[3] = g[7];
        *reinterpret_cast<bf16x4*>(&Vl[vr][base]) = lo;
        *reinterpret_cast<bf16x4*>(&Vl[vr][base + 8]) = hi;
    }
    __syncthreads();

    const f32x4 zero = {0.f, 0.f, 0.f, 0.f};
    bf16x8 onesf;
    #pragma unroll
    for (int i = 0; i < 8; ++i) onesf[i] = (bf16)1.0f;

    // per-qg state, fully unrolled (qg = 0,1 -> independent chains)
    const int qbq[2] = {wid * 32, wid * 32 + 16};
    bf16x8 qf[2];
    const float* bq[2];
    size_t gbase[2];
    bf16x4 g0[2], g1[2];
    f32x4 o0[2], o1[2], ol[2];
    float4 bA0[2], bA1[2], bB0[2], bB1[2];

    #pragma unroll
    for (int qg = 0; qg < 2; ++qg) {
        const int qb = qbq[qg];
        qf[qg] = *reinterpret_cast<const bf16x8*>(&Qh[(qb + l15) * CH_ + l4 * 8]);
        bq[qg] = bias + ((size_t)h * NN_ + qb + l15) * NN_ + l4 * 4;
        gbase[qg] = ((size_t)n * NN_ + qb + l15) * CZ_ + h * CH_;
        g0[qg] = *reinterpret_cast<const bf16x4*>(&Gp[gbase[qg] + l4 * 4]);
        g1[qg] = *reinterpret_cast<const bf16x4*>(&Gp[gbase[qg] + 16 + l4 * 4]);
        o0[qg] = zero; o1[qg] = zero; ol[qg] = zero;
        bA0[qg] = *reinterpret_cast<const float4*>(bq[qg]);
        bA1[qg] = *reinterpret_cast<const float4*>(bq[qg] + 16);
        bB0[qg] = *reinterpret_cast<const float4*>(bq[qg] + 32);
        bB1[qg] = *reinterpret_cast<const float4*>(bq[qg] + 48);
    }

#define ATTN_TP(TP, B0, B1, PRE)                                                   \
    {                                                                              \
        const int kvm = (TP) * 32;                                                 \
        bf16x8 kf0 = *reinterpret_cast<const bf16x8*>(&Kl[kvm + l15][l4 * 8]);     \
        bf16x8 kf1 = *reinterpret_cast<const bf16x8*>(&Kl[kvm + 16 + l15][l4 * 8]);\
        bf16x8 vf0 = *reinterpret_cast<const bf16x8*>(&Vl[l15][kvm + l4 * 8]);     \
        bf16x8 vf1 = *reinterpret_cast<const bf16x8*>(&Vl[16 + l15][kvm + l4 * 8]);\
        f32x4 s0[2], s1[2];                                                        \
        s0[0] = __builtin_amdgcn_mfma_f32_16x16x32_bf16(kf0, qf[0], zero, 0, 0, 0);\
        s1[0] = __builtin_amdgcn_mfma_f32_16x16x32_bf16(kf1, qf[0], zero, 0, 0, 0);\
        s0[1] = __builtin_amdgcn_mfma_f32_16x16x32_bf16(kf0, qf[1], zero, 0, 0, 0);\
        s1[1] = __builtin_amdgcn_mfma_f32_16x16x32_bf16(kf1, qf[1], zero, 0, 0, 0);\
        _Pragma("unroll")                                                          \
        for (int qg = 0; qg < 2; ++qg) {                                           \
            float p0 = __builtin_amdgcn_exp2f(__builtin_fmaf(B0[qg].x, LOG2E_, s0[qg][0])); \
            float p1 = __builtin_amdgcn_exp2f(__builtin_fmaf(B0[qg].y, LOG2E_, s0[qg][1])); \
            float p2 = __builtin_amdgcn_exp2f(__builtin_fmaf(B0[qg].z, LOG2E_, s0[qg][2])); \
            float p3 = __builtin_amdgcn_exp2f(__builtin_fmaf(B0[qg].w, LOG2E_, s0[qg][3])); \
            float p4 = __builtin_amdgcn_exp2f(__builtin_fmaf(B1[qg].x, LOG2E_, s1[qg][0])); \
            float p5 = __builtin_amdgcn_exp2f(__builtin_fmaf(B1[qg].y, LOG2E_, s1[qg][1])); \
            float p6 = __builtin_amdgcn_exp2f(__builtin_fmaf(B1[qg].z, LOG2E_, s1[qg][2])); \
            float p7 = __builtin_amdgcn_exp2f(__builtin_fmaf(B1[qg].w, LOG2E_, s1[qg][3])); \
            u32x4 ww;                                                              \
            ww[0] = pack_bf16(p0, p1); ww[1] = pack_bf16(p2, p3);                  \
            ww[2] = pack_bf16(p4, p5); ww[3] = pack_bf16(p6, p7);                  \
            bf16x8 pf = __builtin_bit_cast(bf16x8, ww);                            \
            if (PRE) { /* refill for TP+2 */                                       \
                B0[qg] = *reinterpret_cast<const float4*>(bq[qg] + ((TP) + 2) * 32);      \
                B1[qg] = *reinterpret_cast<const float4*>(bq[qg] + ((TP) + 2) * 32 + 16); \
            }                                                                      \
            ol[qg] = __builtin_amdgcn_mfma_f32_16x16x32_bf16(onesf, pf, ol[qg], 0, 0, 0); \
            o0[qg] = __builtin_amdgcn_mfma_f32_16x16x32_bf16(vf0, pf, o0[qg], 0, 0, 0);   \
            o1[qg] = __builtin_amdgcn_mfma_f32_16x16x32_bf16(vf1, pf, o1[qg], 0, 0, 0);   \
        }                                                                          \
    }

    #pragma unroll 1
    for (int t2 = 0; t2 < 4; ++t2) {
        ATTN_TP(2 * t2,     bA0, bA1, true);
        ATTN_TP(2 * t2 + 1, bB0, bB1, true);
    }
    ATTN_TP(8, bA0, bA1, false);
    ATTN_TP(9, bB0, bB1, false);
#undef ATTN_TP

    // epilogue per qg: ol[r] holds the full row-sum (all r identical)
    #pragma unroll
    for (int qg = 0; qg < 2; ++qg) {
        const float linv = 1.0f / ol[qg][0];
        bf16x4 h0, h1;
        #pragma unroll
        for (int r = 0; r < 4; ++r) {
            h0[r] = (bf16)(o0[qg][r] * linv * (float)g0[qg][r]);
            h1[r] = (bf16)(o1[qg][r] * linv * (float)g1[qg][r]);
        }
        *reinterpret_cast<bf16x4*>(&Gp[gbase[qg] + l4 * 4]) = h0;
        *reinterpret_cast<bf16x4*>(&Gp[gbase[qg] + 16 + l4 * 4]) = h1;
    }
}

// ---------------------------------------------------------------------------
// Kernel 3: out = og @ wo + bo (fp32). grid 400 x 512 threads; each block
// processes TWO 128-row tiles with one wo staging.
// ---------------------------------------------------------------------------
__global__ __launch_bounds__(512) void oproj_kernel(
    const bf16* __restrict__ og, const float* __restrict__ wo,
    const float* __restrict__ bo, float* __restrict__ out)
{
    __shared__ bf16 wl[128][136];
    const int tid  = threadIdx.x;
    const int lane = tid & 63, wid = tid >> 6;
    const int l15  = lane & 15, l4 = lane >> 4;

    #pragma unroll
    for (int it = 0; it < 8; ++it) {
        int u  = tid + (it << 9);
        int j  = u & 127, k4 = u >> 7;
        bf16x4 t;
        t[0] = (bf16)wo[(k4 * 4 + 0) * CZ_ + j];
        t[1] = (bf16)wo[(k4 * 4 + 1) * CZ_ + j];
        t[2] = (bf16)wo[(k4 * 4 + 2) * CZ_ + j];
        t[3] = (bf16)wo[(k4 * 4 + 3) * CZ_ + j];
        *reinterpret_cast<bf16x4*>(&wl[j][k4 * 4]) = t;
    }
    __syncthreads();

    #pragma unroll 1
    for (int rt = 0; rt < 2; ++rt) {
        const int m0 = (blockIdx.x << 8) + rt * 128;
        const int arow = m0 + wid * 16 + l15;
        bf16x8 af[4];
        #pragma unroll
        for (int ks = 0; ks < 4; ++ks)
            af[ks] = *reinterpret_cast<const bf16x8*>(&og[(size_t)arow * CZ_ + ks * 32 + l4 * 8]);

        f32x4 zero = {0.f, 0.f, 0.f, 0.f};
        f32x4 acc[8];
        #pragma unroll
        for (int ct = 0; ct < 8; ++ct) acc[ct] = zero;
        #pragma unroll
        for (int ks = 0; ks < 4; ++ks)
            #pragma unroll
            for (int ct = 0; ct < 8; ++ct) {
                bf16x8 wf = *reinterpret_cast<const bf16x8*>(&wl[ct * 16 + l15][ks * 32 + l4 * 8]);
                acc[ct] = __builtin_amdgcn_mfma_f32_16x16x32_bf16(af[ks], wf, acc[ct], 0, 0, 0);
            }

        #pragma unroll
        for (int ct = 0; ct < 8; ++ct) {
            const int cout = ct * 16 + l15;
            const float bov = bo[cout];
            #pragma unroll
            for (int r = 0; r < 4; ++r)
                out[(size_t)(m0 + wid * 16 + l4 * 4 + r) * CZ_ + cout] = acc[ct][r] + bov;
        }
    }
}

// ---------------------------------------------------------------------------
extern "C" void kernel_launch(void* const* d_in, const int* in_sizes, int n_in,
                              void* d_out, int out_size, void* d_ws, size_t ws_size,
                              hipStream_t stream) {
    (void)in_sizes; (void)n_in; (void)out_size; (void)ws_size;
    const float* x    = (const float*)d_in[0];
    const float* bias = (const float*)d_in[1];
    const float* wq   = (const float*)d_in[2];
    const float* wk   = (const float*)d_in[3];
    const float* wv   = (const float*)d_in[4];
    const float* wg   = (const float*)d_in[5];
    const float* bg   = (const float*)d_in[6];
    const float* wo   = (const float*)d_in[7];
    const float* bo   = (const float*)d_in[8];
    float* out = (float*)d_out;

    const size_t ELEMS = (size_t)NN_ * NN_ * CZ_;
    bf16* Qp = (bf16*)d_ws;          // 26.2 MB
    bf16* Gp = Qp + ELEMS;           // 26.2 MB
    bf16* Kp = (bf16*)d_out;         // scratch until oproj overwrites
    bf16* Vp = Kp + ELEMS;

    qkvg_kernel<<<dim3(800), 512, 0, stream>>>(x, wq, wk, wv, wg, bg, Qp, Kp, Vp, Gp);
    attn_kernel<<<dim3(1280), 640, 0, stream>>>(Qp, Kp, Vp, Gp, bias);
    oproj_kernel<<<dim3(400), 512, 0, stream>>>(Gp, wo, bo, out);
}

// Round 16
// 138.832 us; speedup vs baseline: 1.0790x; 1.0743x over previous
//
#include <hip/hip_runtime.h>

typedef __bf16 bf16;
typedef __bf16 bf16x8 __attribute__((ext_vector_type(8)));
typedef __bf16 bf16x4 __attribute__((ext_vector_type(4)));
typedef __bf16 bf16x2 __attribute__((ext_vector_type(2)));
typedef float  f32x4  __attribute__((ext_vector_type(4)));
typedef unsigned int u32;
typedef u32 u32x4 __attribute__((ext_vector_type(4)));

#define NN_  320
#define CZ_  128
#define H_   4
#define CH_  32
#define LOG2E_ 1.4426950408889634f

__device__ __forceinline__ u32 pack_bf16(float a, float b) {
    bf16x2 t; t[0] = (bf16)a; t[1] = (bf16)b;
    return __builtin_bit_cast(u32, t);
}

// ---------------------------------------------------------------------------
// Kernel 1: QKVG projections (R13-best). grid 800 x 512 threads.
// T14 weight prefetch: next mat's gather issued under current MFMAs. Direct
// scalar stores (L2 write-combining makes them full-line on eviction; the
// R15 LDS round-trip was measured SLOWER by ~11us).
// Q: [n][h][q][32] bf16, pre-scaled by log2e/sqrt(32) (exp2-domain scores);
// K: [n][h][kv][32]; V: [n][h][32][kv] (transposed); G: [m][128] sigmoid.
// ---------------------------------------------------------------------------
__global__ __launch_bounds__(512) void qkvg_kernel(
    const float* __restrict__ x,
    const float* __restrict__ wq, const float* __restrict__ wk,
    const float* __restrict__ wv, const float* __restrict__ wg,
    const float* __restrict__ bg,
    bf16* __restrict__ Qp, bf16* __restrict__ Kp,
    bf16* __restrict__ Vp, bf16* __restrict__ Gp)
{
    __shared__ bf16 wl[128][136];   // transposed weight wl[j][k], stride 272B
    const int tid  = threadIdx.x;
    const int lane = tid & 63, wid = tid >> 6;
    const int l15  = lane & 15, l4 = lane >> 4;
    const int m0   = blockIdx.x << 7;   // 128 rows per block

    // x row fragments straight to registers (fp32 -> bf16)
    const int arow = m0 + wid * 16 + l15;
    bf16x8 xf[4];
    #pragma unroll
    for (int ks = 0; ks < 4; ++ks) {
        float4 f0 = *reinterpret_cast<const float4*>(x + (size_t)arow * CZ_ + ks * 32 + l4 * 8);
        float4 f1 = *reinterpret_cast<const float4*>(x + (size_t)arow * CZ_ + ks * 32 + l4 * 8 + 4);
        bf16x8 t;
        t[0]=(bf16)f0.x; t[1]=(bf16)f0.y; t[2]=(bf16)f0.z; t[3]=(bf16)f0.w;
        t[4]=(bf16)f1.x; t[5]=(bf16)f1.y; t[6]=(bf16)f1.z; t[7]=(bf16)f1.w;
        xf[ks] = t;
    }

    // row decompositions (blocks can cross n boundaries: 128 does not divide 320)
    int nQ[4], qQ[4];
    #pragma unroll
    for (int r = 0; r < 4; ++r) {
        int m = m0 + wid * 16 + l4 * 4 + r;
        nQ[r] = m / NN_; qQ[r] = m - nQ[r] * NN_;
    }
    const int nV = arow / NN_, qV = arow - nV * NN_;

    const float* Ws[4] = {wq, wk, wv, wg};

    // prime: mat 0 weight gather into registers
    float pw[8][4];
    #pragma unroll
    for (int it = 0; it < 8; ++it) {
        const int u = tid + (it << 9), j = u & 127, k4 = u >> 7;
        #pragma unroll
        for (int r = 0; r < 4; ++r) pw[it][r] = wq[(k4 * 4 + r) * CZ_ + j];
    }

    #pragma unroll
    for (int mat = 0; mat < 4; ++mat) {
        __syncthreads();
        // write staged registers to LDS (bf16, transposed)
        #pragma unroll
        for (int it = 0; it < 8; ++it) {
            const int u = tid + (it << 9), j = u & 127, k4 = u >> 7;
            bf16x4 t;
            t[0] = (bf16)pw[it][0]; t[1] = (bf16)pw[it][1];
            t[2] = (bf16)pw[it][2]; t[3] = (bf16)pw[it][3];
            *reinterpret_cast<bf16x4*>(&wl[j][k4 * 4]) = t;
        }
        __syncthreads();

        // T14: issue next mat's gather now; latency hides under the MFMAs below
        if (mat < 3) {
            const float* wnext = Ws[mat + 1];
            #pragma unroll
            for (int it = 0; it < 8; ++it) {
                const int u = tid + (it << 9), j = u & 127, k4 = u >> 7;
                #pragma unroll
                for (int r = 0; r < 4; ++r) pw[it][r] = wnext[(k4 * 4 + r) * CZ_ + j];
            }
        }

        f32x4 zero = {0.f, 0.f, 0.f, 0.f};
        f32x4 acc[8];
        #pragma unroll
        for (int ct = 0; ct < 8; ++ct) acc[ct] = zero;

        #pragma unroll
        for (int ks = 0; ks < 4; ++ks) {
            #pragma unroll
            for (int ct = 0; ct < 8; ++ct) {
                bf16x8 wf = *reinterpret_cast<const bf16x8*>(&wl[ct * 16 + l15][ks * 32 + l4 * 8]);
                if (mat == 2)  // swapped: D[cout][m] so the V^T store coalesces
                    acc[ct] = __builtin_amdgcn_mfma_f32_16x16x32_bf16(wf, xf[ks], acc[ct], 0, 0, 0);
                else
                    acc[ct] = __builtin_amdgcn_mfma_f32_16x16x32_bf16(xf[ks], wf, acc[ct], 0, 0, 0);
            }
        }

        if (mat == 0) {
            #pragma unroll
            for (int ct = 0; ct < 8; ++ct) {
                const int cout = ct * 16 + l15, hh = cout >> 5, cc = cout & 31;
                #pragma unroll
                for (int r = 0; r < 4; ++r)
                    Qp[(size_t)((nQ[r] * H_ + hh) * NN_ + qQ[r]) * CH_ + cc] =
                        (bf16)(acc[ct][r] * 0.25500003540695464f);  // log2e/sqrt(32)
            }
        } else if (mat == 1) {
            #pragma unroll
            for (int ct = 0; ct < 8; ++ct) {
                const int cout = ct * 16 + l15, hh = cout >> 5, cc = cout & 31;
                #pragma unroll
                for (int r = 0; r < 4; ++r)
                    Kp[(size_t)((nQ[r] * H_ + hh) * NN_ + qQ[r]) * CH_ + cc] = (bf16)acc[ct][r];
            }
        } else if (mat == 2) {
            // D row = cout = ct*16 + l4*4 + r; D col = m-local = l15 (arow)
            #pragma unroll
            for (int ct = 0; ct < 8; ++ct) {
                #pragma unroll
                for (int r = 0; r < 4; ++r) {
                    const int cout = ct * 16 + l4 * 4 + r, hh = cout >> 5, cc = cout & 31;
                    Vp[(size_t)((nV * H_ + hh) * CH_ + cc) * NN_ + qV] = (bf16)acc[ct][r];
                }
            }
        } else {
            #pragma unroll
            for (int ct = 0; ct < 8; ++ct) {
                const int cout = ct * 16 + l15;
                const float bgj = bg[cout];
                #pragma unroll
                for (int r = 0; r < 4; ++r) {
                    float t = acc[ct][r] + bgj;
                    Gp[(size_t)(m0 + wid * 16 + l4 * 4 + r) * CZ_ + cout] =
                        (bf16)(1.0f / (1.0f + __expf(-t)));
                }
            }
        }
    }
}

// ---------------------------------------------------------------------------
// Kernel 2: fused attention + gating (R12-best, 80.8us; setprio proven
// neutral in R15 A/B, kept as-is). grid 1280 = (n,h) h-major XCD-pinned,
// 640 thr = 10 waves. K padded LDS; V sigma-packed (b128 PV reads); dual
// q-group chains; exp2-domain scores; ones-MFMA row-sum.
// Overwrites Gp with o*g (bf16).
// ---------------------------------------------------------------------------
__global__ __launch_bounds__(640, 3) void attn_kernel(
    const bf16* __restrict__ Qp, const bf16* __restrict__ Kp,
    const bf16* __restrict__ Vp, bf16* __restrict__ Gp,
    const float* __restrict__ bias)
{
    __shared__ bf16 Kl[320][40];    // 80B rows
    __shared__ bf16 Vl[32][328];    // 656B rows, sigma-packed cols
    const int tid  = threadIdx.x;
    const int lane = tid & 63;
    const int wid  = tid >> 6;            // 0..9
    const int l15  = lane & 15, l4 = lane >> 4;
    const int gid = blockIdx.x;
    const int lin = (gid & 7) * 160 + (gid >> 3);
    const int h   = lin / NN_;
    const int n   = lin - h * NN_;

    const size_t nh = (size_t)(n * H_ + h);
    const bf16* Kh = Kp + nh * NN_ * CH_;
    const bf16* Vh = Vp + nh * CH_ * NN_;
    const bf16* Qh = Qp + nh * NN_ * CH_;

    // one-shot cooperative staging: 1280 16B chunks each for K and V^T.
    // V chunk (vr, vc): packed base = (vc>>2)*32 + (m&1)*16 + (m>>1)*4, m=vc&3.
    #pragma unroll
    for (int i = 0; i < 2; ++i) {
        int c  = tid + i * 640;
        int kr = c >> 2, kc = (c & 3) * 8;
        *reinterpret_cast<bf16x8*>(&Kl[kr][kc]) =
            *reinterpret_cast<const bf16x8*>(Kh + kr * CH_ + kc);
        int vr = c / 40, vc = c - vr * 40;
        int m = vc & 3, b32 = vc >> 2;
        bf16x8 g = *reinterpret_cast<const bf16x8*>(Vh + vr * NN_ + vc * 8);
        int base = b32 * 32 + (m & 1) * 16 + (m >> 1) * 4;
        bf16x4 lo; lo[0] = g[0]; lo[1] = g[1]; lo[2] = g[2]; lo[3] = g[3];
        bf16x4 hi; hi[0] = g[4]; hi[1] = g[5]; hi[2] = g[6]; hi[3] = g[7];
        *reinterpret_cast<bf16x4*>(&Vl[vr][base]) = lo;
        *reinterpret_cast<bf16x4*>(&Vl[vr][base + 8]) = hi;
    }
    __syncthreads();

    const f32x4 zero = {0.f, 0.f, 0.f, 0.f};
    bf16x8 onesf;
    #pragma unroll
    for (int i = 0; i < 8; ++i) onesf[i] = (bf16)1.0f;

    // per-qg state, fully unrolled (qg = 0,1 -> independent chains)
    const int qbq[2] = {wid * 32, wid * 32 + 16};
    bf16x8 qf[2];
    const float* bq[2];
    size_t gbase[2];
    bf16x4 g0[2], g1[2];
    f32x4 o0[2], o1[2], ol[2];
    float4 bA0[2], bA1[2], bB0[2], bB1[2];

    #pragma unroll
    for (int qg = 0; qg < 2; ++qg) {
        const int qb = qbq[qg];
        qf[qg] = *reinterpret_cast<const bf16x8*>(&Qh[(qb + l15) * CH_ + l4 * 8]);
        bq[qg] = bias + ((size_t)h * NN_ + qb + l15) * NN_ + l4 * 4;
        gbase[qg] = ((size_t)n * NN_ + qb + l15) * CZ_ + h * CH_;
        g0[qg] = *reinterpret_cast<const bf16x4*>(&Gp[gbase[qg] + l4 * 4]);
        g1[qg] = *reinterpret_cast<const bf16x4*>(&Gp[gbase[qg] + 16 + l4 * 4]);
        o0[qg] = zero; o1[qg] = zero; ol[qg] = zero;
        bA0[qg] = *reinterpret_cast<const float4*>(bq[qg]);
        bA1[qg] = *reinterpret_cast<const float4*>(bq[qg] + 16);
        bB0[qg] = *reinterpret_cast<const float4*>(bq[qg] + 32);
        bB1[qg] = *reinterpret_cast<const float4*>(bq[qg] + 48);
    }

#define ATTN_TP(TP, B0, B1, PRE)                                                   \
    {                                                                              \
        const int kvm = (TP) * 32;                                                 \
        bf16x8 kf0 = *reinterpret_cast<const bf16x8*>(&Kl[kvm + l15][l4 * 8]);     \
        bf16x8 kf1 = *reinterpret_cast<const bf16x8*>(&Kl[kvm + 16 + l15][l4 * 8]);\
        bf16x8 vf0 = *reinterpret_cast<const bf16x8*>(&Vl[l15][kvm + l4 * 8]);     \
        bf16x8 vf1 = *reinterpret_cast<const bf16x8*>(&Vl[16 + l15][kvm + l4 * 8]);\
        f32x4 s0[2], s1[2];                                                        \
        __builtin_amdgcn_s_setprio(1);                                             \
        s0[0] = __builtin_amdgcn_mfma_f32_16x16x32_bf16(kf0, qf[0], zero, 0, 0, 0);\
        s1[0] = __builtin_amdgcn_mfma_f32_16x16x32_bf16(kf1, qf[0], zero, 0, 0, 0);\
        s0[1] = __builtin_amdgcn_mfma_f32_16x16x32_bf16(kf0, qf[1], zero, 0, 0, 0);\
        s1[1] = __builtin_amdgcn_mfma_f32_16x16x32_bf16(kf1, qf[1], zero, 0, 0, 0);\
        __builtin_amdgcn_s_setprio(0);                                             \
        _Pragma("unroll")                                                          \
        for (int qg = 0; qg < 2; ++qg) {                                           \
            float p0 = __builtin_amdgcn_exp2f(__builtin_fmaf(B0[qg].x, LOG2E_, s0[qg][0])); \
            float p1 = __builtin_amdgcn_exp2f(__builtin_fmaf(B0[qg].y, LOG2E_, s0[qg][1])); \
            float p2 = __builtin_amdgcn_exp2f(__builtin_fmaf(B0[qg].z, LOG2E_, s0[qg][2])); \
            float p3 = __builtin_amdgcn_exp2f(__builtin_fmaf(B0[qg].w, LOG2E_, s0[qg][3])); \
            float p4 = __builtin_amdgcn_exp2f(__builtin_fmaf(B1[qg].x, LOG2E_, s1[qg][0])); \
            float p5 = __builtin_amdgcn_exp2f(__builtin_fmaf(B1[qg].y, LOG2E_, s1[qg][1])); \
            float p6 = __builtin_amdgcn_exp2f(__builtin_fmaf(B1[qg].z, LOG2E_, s1[qg][2])); \
            float p7 = __builtin_amdgcn_exp2f(__builtin_fmaf(B1[qg].w, LOG2E_, s1[qg][3])); \
            u32x4 ww;                                                              \
            ww[0] = pack_bf16(p0, p1); ww[1] = pack_bf16(p2, p3);                  \
            ww[2] = pack_bf16(p4, p5); ww[3] = pack_bf16(p6, p7);                  \
            bf16x8 pf = __builtin_bit_cast(bf16x8, ww);                            \
            if (PRE) { /* refill for TP+2 */                                       \
                B0[qg] = *reinterpret_cast<const float4*>(bq[qg] + ((TP) + 2) * 32);      \
                B1[qg] = *reinterpret_cast<const float4*>(bq[qg] + ((TP) + 2) * 32 + 16); \
            }                                                                      \
            __builtin_amdgcn_s_setprio(1);                                         \
            ol[qg] = __builtin_amdgcn_mfma_f32_16x16x32_bf16(onesf, pf, ol[qg], 0, 0, 0); \
            o0[qg] = __builtin_amdgcn_mfma_f32_16x16x32_bf16(vf0, pf, o0[qg], 0, 0, 0);   \
            o1[qg] = __builtin_amdgcn_mfma_f32_16x16x32_bf16(vf1, pf, o1[qg], 0, 0, 0);   \
            __builtin_amdgcn_s_setprio(0);                                         \
        }                                                                          \
    }

    #pragma unroll 1
    for (int t2 = 0; t2 < 4; ++t2) {
        ATTN_TP(2 * t2,     bA0, bA1, true);
        ATTN_TP(2 * t2 + 1, bB0, bB1, true);
    }
    ATTN_TP(8, bA0, bA1, false);
    ATTN_TP(9, bB0, bB1, false);
#undef ATTN_TP

    // epilogue per qg: ol[r] holds the full row-sum (all r identical)
    #pragma unroll
    for (int qg = 0; qg < 2; ++qg) {
        const float linv = 1.0f / ol[qg][0];
        bf16x4 h0, h1;
        #pragma unroll
        for (int r = 0; r < 4; ++r) {
            h0[r] = (bf16)(o0[qg][r] * linv * (float)g0[qg][r]);
            h1[r] = (bf16)(o1[qg][r] * linv * (float)g1[qg][r]);
        }
        *reinterpret_cast<bf16x4*>(&Gp[gbase[qg] + l4 * 4]) = h0;
        *reinterpret_cast<bf16x4*>(&Gp[gbase[qg] + 16 + l4 * 4]) = h1;
    }
}

// ---------------------------------------------------------------------------
// Kernel 3: out = og @ wo + bo (fp32) (R13-best). grid 400 x 512 threads;
// each block processes TWO 128-row tiles with one wo staging.
// ---------------------------------------------------------------------------
__global__ __launch_bounds__(512) void oproj_kernel(
    const bf16* __restrict__ og, const float* __restrict__ wo,
    const float* __restrict__ bo, float* __restrict__ out)
{
    __shared__ bf16 wl[128][136];
    const int tid  = threadIdx.x;
    const int lane = tid & 63, wid = tid >> 6;
    const int l15  = lane & 15, l4 = lane >> 4;

    #pragma unroll
    for (int it = 0; it < 8; ++it) {
        int u  = tid + (it << 9);
        int j  = u & 127, k4 = u >> 7;
        bf16x4 t;
        t[0] = (bf16)wo[(k4 * 4 + 0) * CZ_ + j];
        t[1] = (bf16)wo[(k4 * 4 + 1) * CZ_ + j];
        t[2] = (bf16)wo[(k4 * 4 + 2) * CZ_ + j];
        t[3] = (bf16)wo[(k4 * 4 + 3) * CZ_ + j];
        *reinterpret_cast<bf16x4*>(&wl[j][k4 * 4]) = t;
    }
    __syncthreads();

    #pragma unroll 1
    for (int rt = 0; rt < 2; ++rt) {
        const int m0 = (blockIdx.x << 8) + rt * 128;
        const int arow = m0 + wid * 16 + l15;
        bf16x8 af[4];
        #pragma unroll
        for (int ks = 0; ks < 4; ++ks)
            af[ks] = *reinterpret_cast<const bf16x8*>(&og[(size_t)arow * CZ_ + ks * 32 + l4 * 8]);

        f32x4 zero = {0.f, 0.f, 0.f, 0.f};
        f32x4 acc[8];
        #pragma unroll
        for (int ct = 0; ct < 8; ++ct) acc[ct] = zero;
        #pragma unroll
        for (int ks = 0; ks < 4; ++ks)
            #pragma unroll
            for (int ct = 0; ct < 8; ++ct) {
                bf16x8 wf = *reinterpret_cast<const bf16x8*>(&wl[ct * 16 + l15][ks * 32 + l4 * 8]);
                acc[ct] = __builtin_amdgcn_mfma_f32_16x16x32_bf16(af[ks], wf, acc[ct], 0, 0, 0);
            }

        #pragma unroll
        for (int ct = 0; ct < 8; ++ct) {
            const int cout = ct * 16 + l15;
            const float bov = bo[cout];
            #pragma unroll
            for (int r = 0; r < 4; ++r)
                out[(size_t)(m0 + wid * 16 + l4 * 4 + r) * CZ_ + cout] = acc[ct][r] + bov;
        }
    }
}

// ---------------------------------------------------------------------------
extern "C" void kernel_launch(void* const* d_in, const int* in_sizes, int n_in,
                              void* d_out, int out_size, void* d_ws, size_t ws_size,
                              hipStream_t stream) {
    (void)in_sizes; (void)n_in; (void)out_size; (void)ws_size;
    const float* x    = (const float*)d_in[0];
    const float* bias = (const float*)d_in[1];
    const float* wq   = (const float*)d_in[2];
    const float* wk   = (const float*)d_in[3];
    const float* wv   = (const float*)d_in[4];
    const float* wg   = (const float*)d_in[5];
    const float* bg   = (const float*)d_in[6];
    const float* wo   = (const float*)d_in[7];
    const float* bo   = (const float*)d_in[8];
    float* out = (float*)d_out;

    const size_t ELEMS = (size_t)NN_ * NN_ * CZ_;
    bf16* Qp = (bf16*)d_ws;          // 26.2 MB
    bf16* Gp = Qp + ELEMS;           // 26.2 MB
    bf16* Kp = (bf16*)d_out;         // scratch until oproj overwrites
    bf16* Vp = Kp + ELEMS;

    qkvg_kernel<<<dim3(800), 512, 0, stream>>>(x, wq, wk, wv, wg, bg, Qp, Kp, Vp, Gp);
    attn_kernel<<<dim3(1280), 640, 0, stream>>>(Qp, Kp, Vp, Gp, bias);
    oproj_kernel<<<dim3(400), 512, 0, stream>>>(Gp, wo, bo, out);
}

// Round 17
// 136.442 us; speedup vs baseline: 1.0979x; 1.0175x over previous
//
#include <hip/hip_runtime.h>

typedef __bf16 bf16;
typedef __bf16 bf16x8 __attribute__((ext_vector_type(8)));
typedef __bf16 bf16x4 __attribute__((ext_vector_type(4)));
typedef __bf16 bf16x2 __attribute__((ext_vector_type(2)));
typedef float  f32x4  __attribute__((ext_vector_type(4)));
typedef unsigned int u32;
typedef u32 u32x4 __attribute__((ext_vector_type(4)));

#define NN_  320
#define CZ_  128
#define H_   4
#define CH_  32
#define LOG2E_ 1.4426950408889634f

__device__ __forceinline__ u32 pack_bf16(float a, float b) {
    bf16x2 t; t[0] = (bf16)a; t[1] = (bf16)b;
    return __builtin_bit_cast(u32, t);
}

// ---------------------------------------------------------------------------
// Kernel 1: QKVG projections (R13-best). grid 800 x 512 threads.
// T14 weight prefetch: next mat's gather issued under current MFMAs.
// Q: [n][h][q][32] bf16, pre-scaled by log2e/sqrt(32) (exp2-domain scores);
// K: [n][h][kv][32]; V: [n][h][32][kv] (transposed); G: [m][128] sigmoid.
// ---------------------------------------------------------------------------
__global__ __launch_bounds__(512) void qkvg_kernel(
    const float* __restrict__ x,
    const float* __restrict__ wq, const float* __restrict__ wk,
    const float* __restrict__ wv, const float* __restrict__ wg,
    const float* __restrict__ bg,
    bf16* __restrict__ Qp, bf16* __restrict__ Kp,
    bf16* __restrict__ Vp, bf16* __restrict__ Gp)
{
    __shared__ bf16 wl[128][136];   // transposed weight wl[j][k], stride 272B
    const int tid  = threadIdx.x;
    const int lane = tid & 63, wid = tid >> 6;
    const int l15  = lane & 15, l4 = lane >> 4;
    const int m0   = blockIdx.x << 7;   // 128 rows per block

    // x row fragments straight to registers (fp32 -> bf16)
    const int arow = m0 + wid * 16 + l15;
    bf16x8 xf[4];
    #pragma unroll
    for (int ks = 0; ks < 4; ++ks) {
        float4 f0 = *reinterpret_cast<const float4*>(x + (size_t)arow * CZ_ + ks * 32 + l4 * 8);
        float4 f1 = *reinterpret_cast<const float4*>(x + (size_t)arow * CZ_ + ks * 32 + l4 * 8 + 4);
        bf16x8 t;
        t[0]=(bf16)f0.x; t[1]=(bf16)f0.y; t[2]=(bf16)f0.z; t[3]=(bf16)f0.w;
        t[4]=(bf16)f1.x; t[5]=(bf16)f1.y; t[6]=(bf16)f1.z; t[7]=(bf16)f1.w;
        xf[ks] = t;
    }

    // row decompositions (blocks can cross n boundaries: 128 does not divide 320)
    int nQ[4], qQ[4];
    #pragma unroll
    for (int r = 0; r < 4; ++r) {
        int m = m0 + wid * 16 + l4 * 4 + r;
        nQ[r] = m / NN_; qQ[r] = m - nQ[r] * NN_;
    }
    const int nV = arow / NN_, qV = arow - nV * NN_;

    const float* Ws[4] = {wq, wk, wv, wg};

    // prime: mat 0 weight gather into registers
    float pw[8][4];
    #pragma unroll
    for (int it = 0; it < 8; ++it) {
        const int u = tid + (it << 9), j = u & 127, k4 = u >> 7;
        #pragma unroll
        for (int r = 0; r < 4; ++r) pw[it][r] = wq[(k4 * 4 + r) * CZ_ + j];
    }

    #pragma unroll
    for (int mat = 0; mat < 4; ++mat) {
        __syncthreads();
        // write staged registers to LDS (bf16, transposed)
        #pragma unroll
        for (int it = 0; it < 8; ++it) {
            const int u = tid + (it << 9), j = u & 127, k4 = u >> 7;
            bf16x4 t;
            t[0] = (bf16)pw[it][0]; t[1] = (bf16)pw[it][1];
            t[2] = (bf16)pw[it][2]; t[3] = (bf16)pw[it][3];
            *reinterpret_cast<bf16x4*>(&wl[j][k4 * 4]) = t;
        }
        __syncthreads();

        // T14: issue next mat's gather now; latency hides under the MFMAs below
        if (mat < 3) {
            const float* wnext = Ws[mat + 1];
            #pragma unroll
            for (int it = 0; it < 8; ++it) {
                const int u = tid + (it << 9), j = u & 127, k4 = u >> 7;
                #pragma unroll
                for (int r = 0; r < 4; ++r) pw[it][r] = wnext[(k4 * 4 + r) * CZ_ + j];
            }
        }

        f32x4 zero = {0.f, 0.f, 0.f, 0.f};
        f32x4 acc[8];
        #pragma unroll
        for (int ct = 0; ct < 8; ++ct) acc[ct] = zero;

        #pragma unroll
        for (int ks = 0; ks < 4; ++ks) {
            #pragma unroll
            for (int ct = 0; ct < 8; ++ct) {
                bf16x8 wf = *reinterpret_cast<const bf16x8*>(&wl[ct * 16 + l15][ks * 32 + l4 * 8]);
                if (mat == 2)  // swapped: D[cout][m] so the V^T store coalesces
                    acc[ct] = __builtin_amdgcn_mfma_f32_16x16x32_bf16(wf, xf[ks], acc[ct], 0, 0, 0);
                else
                    acc[ct] = __builtin_amdgcn_mfma_f32_16x16x32_bf16(xf[ks], wf, acc[ct], 0, 0, 0);
            }
        }

        if (mat == 0) {
            #pragma unroll
            for (int ct = 0; ct < 8; ++ct) {
                const int cout = ct * 16 + l15, hh = cout >> 5, cc = cout & 31;
                #pragma unroll
                for (int r = 0; r < 4; ++r)
                    Qp[(size_t)((nQ[r] * H_ + hh) * NN_ + qQ[r]) * CH_ + cc] =
                        (bf16)(acc[ct][r] * 0.25500003540695464f);  // log2e/sqrt(32)
            }
        } else if (mat == 1) {
            #pragma unroll
            for (int ct = 0; ct < 8; ++ct) {
                const int cout = ct * 16 + l15, hh = cout >> 5, cc = cout & 31;
                #pragma unroll
                for (int r = 0; r < 4; ++r)
                    Kp[(size_t)((nQ[r] * H_ + hh) * NN_ + qQ[r]) * CH_ + cc] = (bf16)acc[ct][r];
            }
        } else if (mat == 2) {
            // D row = cout = ct*16 + l4*4 + r; D col = m-local = l15 (arow)
            #pragma unroll
            for (int ct = 0; ct < 8; ++ct) {
                #pragma unroll
                for (int r = 0; r < 4; ++r) {
                    const int cout = ct * 16 + l4 * 4 + r, hh = cout >> 5, cc = cout & 31;
                    Vp[(size_t)((nV * H_ + hh) * CH_ + cc) * NN_ + qV] = (bf16)acc[ct][r];
                }
            }
        } else {
            #pragma unroll
            for (int ct = 0; ct < 8; ++ct) {
                const int cout = ct * 16 + l15;
                const float bgj = bg[cout];
                #pragma unroll
                for (int r = 0; r < 4; ++r) {
                    float t = acc[ct][r] + bgj;
                    Gp[(size_t)(m0 + wid * 16 + l4 * 4 + r) * CZ_ + cout] =
                        (bf16)(1.0f / (1.0f + __expf(-t)));
                }
            }
        }
    }
}

// ---------------------------------------------------------------------------
// Kernel 2: fused attention + gating. R16 base (80.8us) with two changes:
// (1) PROLOGUE HOISTING: Q, gate, and first bias loads are issued BEFORE the
//     staging barrier (which already drains vmcnt(0)) -- post-barrier the
//     wave starts MFMAs from registers instead of serializing ~1k cycles of
//     dependent global loads per block generation (~5 generations/CU).
// (2) body loop fully unrolled (cross-body LDS-read hoisting).
// grid 1280 = (n,h) h-major XCD-pinned, 640 thr = 10 waves. K padded LDS;
// V sigma-packed (b128 PV reads); dual q-group chains; exp2-domain scores;
// ones-MFMA row-sum. Overwrites Gp with o*g (bf16).
// ---------------------------------------------------------------------------
__global__ __launch_bounds__(640, 3) void attn_kernel(
    const bf16* __restrict__ Qp, const bf16* __restrict__ Kp,
    const bf16* __restrict__ Vp, bf16* __restrict__ Gp,
    const float* __restrict__ bias)
{
    __shared__ bf16 Kl[320][40];    // 80B rows
    __shared__ bf16 Vl[32][328];    // 656B rows, sigma-packed cols
    const int tid  = threadIdx.x;
    const int lane = tid & 63;
    const int wid  = tid >> 6;            // 0..9
    const int l15  = lane & 15, l4 = lane >> 4;
    const int gid = blockIdx.x;
    const int lin = (gid & 7) * 160 + (gid >> 3);
    const int h   = lin / NN_;
    const int n   = lin - h * NN_;

    const size_t nh = (size_t)(n * H_ + h);
    const bf16* Kh = Kp + nh * NN_ * CH_;
    const bf16* Vh = Vp + nh * CH_ * NN_;
    const bf16* Qh = Qp + nh * NN_ * CH_;

    // ---- prologue hoisting: issue per-wave global loads FIRST ----
    const int qbq[2] = {wid * 32, wid * 32 + 16};
    bf16x8 qf[2];
    const float* bq[2];
    size_t gbase[2];
    bf16x4 g0[2], g1[2];
    float4 bA0[2], bA1[2], bB0[2], bB1[2];
    #pragma unroll
    for (int qg = 0; qg < 2; ++qg) {
        const int qb = qbq[qg];
        qf[qg] = *reinterpret_cast<const bf16x8*>(&Qh[(qb + l15) * CH_ + l4 * 8]);
        bq[qg] = bias + ((size_t)h * NN_ + qb + l15) * NN_ + l4 * 4;
        gbase[qg] = ((size_t)n * NN_ + qb + l15) * CZ_ + h * CH_;
        g0[qg] = *reinterpret_cast<const bf16x4*>(&Gp[gbase[qg] + l4 * 4]);
        g1[qg] = *reinterpret_cast<const bf16x4*>(&Gp[gbase[qg] + 16 + l4 * 4]);
        bA0[qg] = *reinterpret_cast<const float4*>(bq[qg]);
        bA1[qg] = *reinterpret_cast<const float4*>(bq[qg] + 16);
        bB0[qg] = *reinterpret_cast<const float4*>(bq[qg] + 32);
        bB1[qg] = *reinterpret_cast<const float4*>(bq[qg] + 48);
    }

    // ---- cooperative staging: 1280 16B chunks each for K and V^T ----
    // V chunk (vr, vc): packed base = (vc>>2)*32 + (m&1)*16 + (m>>1)*4, m=vc&3.
    #pragma unroll
    for (int i = 0; i < 2; ++i) {
        int c  = tid + i * 640;
        int kr = c >> 2, kc = (c & 3) * 8;
        *reinterpret_cast<bf16x8*>(&Kl[kr][kc]) =
            *reinterpret_cast<const bf16x8*>(Kh + kr * CH_ + kc);
        int vr = c / 40, vc = c - vr * 40;
        int m = vc & 3, b32 = vc >> 2;
        bf16x8 g = *reinterpret_cast<const bf16x8*>(Vh + vr * NN_ + vc * 8);
        int base = b32 * 32 + (m & 1) * 16 + (m >> 1) * 4;
        bf16x4 lo; lo[0] = g[0]; lo[1] = g[1]; lo[2] = g[2]; lo[3] = g[3];
        bf16x4 hi; hi[0] = g[4]; hi[1] = g[5]; hi[2] = g[6]; hi[3] = g[7];
        *reinterpret_cast<bf16x4*>(&Vl[vr][base]) = lo;
        *reinterpret_cast<bf16x4*>(&Vl[vr][base + 8]) = hi;
    }
    __syncthreads();

    const f32x4 zero = {0.f, 0.f, 0.f, 0.f};
    bf16x8 onesf;
    #pragma unroll
    for (int i = 0; i < 8; ++i) onesf[i] = (bf16)1.0f;

    f32x4 o0[2], o1[2], ol[2];
    #pragma unroll
    for (int qg = 0; qg < 2; ++qg) { o0[qg] = zero; o1[qg] = zero; ol[qg] = zero; }

#define ATTN_TP(TP, B0, B1, PRE)                                                   \
    {                                                                              \
        const int kvm = (TP) * 32;                                                 \
        bf16x8 kf0 = *reinterpret_cast<const bf16x8*>(&Kl[kvm + l15][l4 * 8]);     \
        bf16x8 kf1 = *reinterpret_cast<const bf16x8*>(&Kl[kvm + 16 + l15][l4 * 8]);\
        bf16x8 vf0 = *reinterpret_cast<const bf16x8*>(&Vl[l15][kvm + l4 * 8]);     \
        bf16x8 vf1 = *reinterpret_cast<const bf16x8*>(&Vl[16 + l15][kvm + l4 * 8]);\
        f32x4 s0[2], s1[2];                                                        \
        __builtin_amdgcn_s_setprio(1);                                             \
        s0[0] = __builtin_amdgcn_mfma_f32_16x16x32_bf16(kf0, qf[0], zero, 0, 0, 0);\
        s1[0] = __builtin_amdgcn_mfma_f32_16x16x32_bf16(kf1, qf[0], zero, 0, 0, 0);\
        s0[1] = __builtin_amdgcn_mfma_f32_16x16x32_bf16(kf0, qf[1], zero, 0, 0, 0);\
        s1[1] = __builtin_amdgcn_mfma_f32_16x16x32_bf16(kf1, qf[1], zero, 0, 0, 0);\
        __builtin_amdgcn_s_setprio(0);                                             \
        _Pragma("unroll")                                                          \
        for (int qg = 0; qg < 2; ++qg) {                                           \
            float p0 = __builtin_amdgcn_exp2f(__builtin_fmaf(B0[qg].x, LOG2E_, s0[qg][0])); \
            float p1 = __builtin_amdgcn_exp2f(__builtin_fmaf(B0[qg].y, LOG2E_, s0[qg][1])); \
            float p2 = __builtin_amdgcn_exp2f(__builtin_fmaf(B0[qg].z, LOG2E_, s0[qg][2])); \
            float p3 = __builtin_amdgcn_exp2f(__builtin_fmaf(B0[qg].w, LOG2E_, s0[qg][3])); \
            float p4 = __builtin_amdgcn_exp2f(__builtin_fmaf(B1[qg].x, LOG2E_, s1[qg][0])); \
            float p5 = __builtin_amdgcn_exp2f(__builtin_fmaf(B1[qg].y, LOG2E_, s1[qg][1])); \
            float p6 = __builtin_amdgcn_exp2f(__builtin_fmaf(B1[qg].z, LOG2E_, s1[qg][2])); \
            float p7 = __builtin_amdgcn_exp2f(__builtin_fmaf(B1[qg].w, LOG2E_, s1[qg][3])); \
            u32x4 ww;                                                              \
            ww[0] = pack_bf16(p0, p1); ww[1] = pack_bf16(p2, p3);                  \
            ww[2] = pack_bf16(p4, p5); ww[3] = pack_bf16(p6, p7);                  \
            bf16x8 pf = __builtin_bit_cast(bf16x8, ww);                            \
            if (PRE) { /* refill for TP+2 */                                       \
                B0[qg] = *reinterpret_cast<const float4*>(bq[qg] + ((TP) + 2) * 32);      \
                B1[qg] = *reinterpret_cast<const float4*>(bq[qg] + ((TP) + 2) * 32 + 16); \
            }                                                                      \
            __builtin_amdgcn_s_setprio(1);                                         \
            ol[qg] = __builtin_amdgcn_mfma_f32_16x16x32_bf16(onesf, pf, ol[qg], 0, 0, 0); \
            o0[qg] = __builtin_amdgcn_mfma_f32_16x16x32_bf16(vf0, pf, o0[qg], 0, 0, 0);   \
            o1[qg] = __builtin_amdgcn_mfma_f32_16x16x32_bf16(vf1, pf, o1[qg], 0, 0, 0);   \
            __builtin_amdgcn_s_setprio(0);                                         \
        }                                                                          \
    }

    // fully unrolled body sequence (cross-body scheduling freedom)
    ATTN_TP(0, bA0, bA1, true);
    ATTN_TP(1, bB0, bB1, true);
    ATTN_TP(2, bA0, bA1, true);
    ATTN_TP(3, bB0, bB1, true);
    ATTN_TP(4, bA0, bA1, true);
    ATTN_TP(5, bB0, bB1, true);
    ATTN_TP(6, bA0, bA1, true);
    ATTN_TP(7, bB0, bB1, true);
    ATTN_TP(8, bA0, bA1, false);
    ATTN_TP(9, bB0, bB1, false);
#undef ATTN_TP

    // epilogue per qg: ol[r] holds the full row-sum (all r identical)
    #pragma unroll
    for (int qg = 0; qg < 2; ++qg) {
        const float linv = 1.0f / ol[qg][0];
        bf16x4 h0, h1;
        #pragma unroll
        for (int r = 0; r < 4; ++r) {
            h0[r] = (bf16)(o0[qg][r] * linv * (float)g0[qg][r]);
            h1[r] = (bf16)(o1[qg][r] * linv * (float)g1[qg][r]);
        }
        *reinterpret_cast<bf16x4*>(&Gp[gbase[qg] + l4 * 4]) = h0;
        *reinterpret_cast<bf16x4*>(&Gp[gbase[qg] + 16 + l4 * 4]) = h1;
    }
}

// ---------------------------------------------------------------------------
// Kernel 3: out = og @ wo + bo (fp32) (R13-best). grid 400 x 512 threads;
// each block processes TWO 128-row tiles with one wo staging.
// ---------------------------------------------------------------------------
__global__ __launch_bounds__(512) void oproj_kernel(
    const bf16* __restrict__ og, const float* __restrict__ wo,
    const float* __restrict__ bo, float* __restrict__ out)
{
    __shared__ bf16 wl[128][136];
    const int tid  = threadIdx.x;
    const int lane = tid & 63, wid = tid >> 6;
    const int l15  = lane & 15, l4 = lane >> 4;

    #pragma unroll
    for (int it = 0; it < 8; ++it) {
        int u  = tid + (it << 9);
        int j  = u & 127, k4 = u >> 7;
        bf16x4 t;
        t[0] = (bf16)wo[(k4 * 4 + 0) * CZ_ + j];
        t[1] = (bf16)wo[(k4 * 4 + 1) * CZ_ + j];
        t[2] = (bf16)wo[(k4 * 4 + 2) * CZ_ + j];
        t[3] = (bf16)wo[(k4 * 4 + 3) * CZ_ + j];
        *reinterpret_cast<bf16x4*>(&wl[j][k4 * 4]) = t;
    }
    __syncthreads();

    #pragma unroll 1
    for (int rt = 0; rt < 2; ++rt) {
        const int m0 = (blockIdx.x << 8) + rt * 128;
        const int arow = m0 + wid * 16 + l15;
        bf16x8 af[4];
        #pragma unroll
        for (int ks = 0; ks < 4; ++ks)
            af[ks] = *reinterpret_cast<const bf16x8*>(&og[(size_t)arow * CZ_ + ks * 32 + l4 * 8]);

        f32x4 zero = {0.f, 0.f, 0.f, 0.f};
        f32x4 acc[8];
        #pragma unroll
        for (int ct = 0; ct < 8; ++ct) acc[ct] = zero;
        #pragma unroll
        for (int ks = 0; ks < 4; ++ks)
            #pragma unroll
            for (int ct = 0; ct < 8; ++ct) {
                bf16x8 wf = *reinterpret_cast<const bf16x8*>(&wl[ct * 16 + l15][ks * 32 + l4 * 8]);
                acc[ct] = __builtin_amdgcn_mfma_f32_16x16x32_bf16(af[ks], wf, acc[ct], 0, 0, 0);
            }

        #pragma unroll
        for (int ct = 0; ct < 8; ++ct) {
            const int cout = ct * 16 + l15;
            const float bov = bo[cout];
            #pragma unroll
            for (int r = 0; r < 4; ++r)
                out[(size_t)(m0 + wid * 16 + l4 * 4 + r) * CZ_ + cout] = acc[ct][r] + bov;
        }
    }
}

// ---------------------------------------------------------------------------
extern "C" void kernel_launch(void* const* d_in, const int* in_sizes, int n_in,
                              void* d_out, int out_size, void* d_ws, size_t ws_size,
                              hipStream_t stream) {
    (void)in_sizes; (void)n_in; (void)out_size; (void)ws_size;
    const float* x    = (const float*)d_in[0];
    const float* bias = (const float*)d_in[1];
    const float* wq   = (const float*)d_in[2];
    const float* wk   = (const float*)d_in[3];
    const float* wv   = (const float*)d_in[4];
    const float* wg   = (const float*)d_in[5];
    const float* bg   = (const float*)d_in[6];
    const float* wo   = (const float*)d_in[7];
    const float* bo   = (const float*)d_in[8];
    float* out = (float*)d_out;

    const size_t ELEMS = (size_t)NN_ * NN_ * CZ_;
    bf16* Qp = (bf16*)d_ws;          // 26.2 MB
    bf16* Gp = Qp + ELEMS;           // 26.2 MB
    bf16* Kp = (bf16*)d_out;         // scratch until oproj overwrites
    bf16* Vp = Kp + ELEMS;

    qkvg_kernel<<<dim3(800), 512, 0, stream>>>(x, wq, wk, wv, wg, bg, Qp, Kp, Vp, Gp);
    attn_kernel<<<dim3(1280), 640, 0, stream>>>(Qp, Kp, Vp, Gp, bias);
    oproj_kernel<<<dim3(400), 512, 0, stream>>>(Gp, wo, bo, out);
}